// Round 13
// baseline (436.169 us; speedup 1.0000x reference)
//
#include <hip/hip_runtime.h>

#define T_STEPS 4
#define V_TH 1.0f

// Native clang vector type: __builtin_nontemporal_* requires a pointer to
// scalar or native vector — HIP's float4 (HIP_vector_type class) is rejected.
typedef float f32x4 __attribute__((ext_vector_type(4)));

__global__ __launch_bounds__(256) void OnlineNeuron_kernel(
    const f32x4* __restrict__ x,
    const float* __restrict__ alpha_1,
    const float* __restrict__ beta_1,
    const float* __restrict__ alpha_2,
    const float* __restrict__ beta_2,
    f32x4* __restrict__ out,
    long long n4)           // elements per timestep plane, in float4 units
{
    // scalar gates: broadcast loads (L2-hit), computed once per thread
    const float a1 = 1.0f / (1.0f + expf(-alpha_1[0])) - 0.5f;
    const float b1 = 1.0f / (1.0f + expf(-beta_1[0]))  - 0.5f;
    const float a2 = 1.0f / (1.0f + expf(-alpha_2[0])) + 0.5f;
    const float b2 = 1.0f / (1.0f + expf(-beta_2[0]))  + 0.5f;

    const long long stride = (long long)gridDim.x * blockDim.x;
    const long long gid    = (long long)blockIdx.x * blockDim.x + threadIdx.x;

    // 2-tile unroll: issue all 8 plane-loads (2 tiles x 4 timesteps) before
    // any compute/store -> doubles per-thread outstanding loads (MLP probe).
    for (long long i = gid; i < n4; i += 2 * stride) {
        const long long j    = i + stride;
        const bool      hasj = (j < n4);

        f32x4 xa[T_STEPS];
        f32x4 xb[T_STEPS];

        #pragma unroll
        for (int t = 0; t < T_STEPS; ++t)
            xa[t] = __builtin_nontemporal_load(x + (long long)t * n4 + i);
        if (hasj) {
            #pragma unroll
            for (int t = 0; t < T_STEPS; ++t)
                xb[t] = __builtin_nontemporal_load(x + (long long)t * n4 + j);
        }

        f32x4 vda = (f32x4)(0.0f), vsa = (f32x4)(0.5f * V_TH);
        f32x4 vdb = (f32x4)(0.0f), vsb = (f32x4)(0.5f * V_TH);

        #pragma unroll
        for (int t = 0; t < T_STEPS; ++t) {
            f32x4 oa;
            #pragma unroll
            for (int c = 0; c < 4; ++c) {
                vda[c] = a1 * vda[c] + b1 * vsa[c] + xa[t][c];
                vsa[c] = a2 * vsa[c] + b2 * vda[c];
                float s = (vsa[c] - V_TH >= 0.0f) ? V_TH : 0.0f;
                oa[c] = s;
                vsa[c] -= s;
            }
            __builtin_nontemporal_store(oa, out + (long long)t * n4 + i);

            if (hasj) {
                f32x4 ob;
                #pragma unroll
                for (int c = 0; c < 4; ++c) {
                    vdb[c] = a1 * vdb[c] + b1 * vsb[c] + xb[t][c];
                    vsb[c] = a2 * vsb[c] + b2 * vdb[c];
                    float s = (vsb[c] - V_TH >= 0.0f) ? V_TH : 0.0f;
                    ob[c] = s;
                    vsb[c] -= s;
                }
                __builtin_nontemporal_store(ob, out + (long long)t * n4 + j);
            }
        }
    }
}

// scalar tail kernel (robustness; unused when plane size % 4 == 0)
__global__ __launch_bounds__(64) void OnlineNeuron_tail(
    const float* __restrict__ x,
    const float* __restrict__ alpha_1,
    const float* __restrict__ beta_1,
    const float* __restrict__ alpha_2,
    const float* __restrict__ beta_2,
    float* __restrict__ out,
    long long base, long long n)   // elements [base, base+n) of each plane
{
    const float a1 = 1.0f / (1.0f + expf(-alpha_1[0])) - 0.5f;
    const float b1 = 1.0f / (1.0f + expf(-beta_1[0]))  - 0.5f;
    const float a2 = 1.0f / (1.0f + expf(-alpha_2[0])) + 0.5f;
    const float b2 = 1.0f / (1.0f + expf(-beta_2[0]))  + 0.5f;
    const long long nplane = base + n;

    long long i = (long long)blockIdx.x * blockDim.x + threadIdx.x;
    if (i >= n) return;
    long long idx = base + i;

    float vd = 0.f, vs = 0.5f * V_TH;
    #pragma unroll
    for (int t = 0; t < T_STEPS; ++t) {
        float xv = x[(long long)t * nplane + idx];
        vd = a1 * vd + b1 * vs + xv;
        vs = a2 * vs + b2 * vd;
        float s = (vs - V_TH >= 0.0f) ? V_TH : 0.0f;
        out[(long long)t * nplane + idx] = s;
        vs -= s;
    }
}

extern "C" void kernel_launch(void* const* d_in, const int* in_sizes, int n_in,
                              void* d_out, int out_size, void* d_ws, size_t ws_size,
                              hipStream_t stream) {
    const float* x  = (const float*)d_in[0];
    const float* a1 = (const float*)d_in[1];
    const float* b1 = (const float*)d_in[2];
    const float* a2 = (const float*)d_in[3];
    const float* b2 = (const float*)d_in[4];
    float* out = (float*)d_out;

    const long long total = (long long)in_sizes[0];
    const long long N     = total / T_STEPS;   // elements per timestep plane
    const long long n4    = N / 4;             // float4 units per plane
    const long long tail  = N - n4 * 4;

    const int block = 256;
    long long want_blocks = (n4 + block - 1) / block;
    int grid = (int)(want_blocks < 2048 ? (want_blocks > 0 ? want_blocks : 1) : 2048);

    OnlineNeuron_kernel<<<grid, block, 0, stream>>>(
        (const f32x4*)x, a1, b1, a2, b2, (f32x4*)out, n4);

    if (tail > 0) {
        int tgrid = (int)((tail + 63) / 64);
        OnlineNeuron_tail<<<tgrid, 64, 0, stream>>>(
            x, a1, b1, a2, b2, out, n4 * 4, tail);
    }
}

// Round 16
// 423.552 us; speedup vs baseline: 1.0298x; 1.0298x over previous
//
#include <hip/hip_runtime.h>

#define T_STEPS 4
#define V_TH 1.0f

// Native clang vector type: __builtin_nontemporal_* requires a pointer to
// scalar or native vector — HIP's float4 (HIP_vector_type class) is rejected.
typedef float f32x4 __attribute__((ext_vector_type(4)));

// Exact-grid: one float4-tile per thread, no grid-stride loop.
// (Round-13 showed per-thread MLP is not the limiter; round-11 body wins.)
__global__ __launch_bounds__(256) void OnlineNeuron_kernel(
    const f32x4* __restrict__ x,
    const float* __restrict__ alpha_1,
    const float* __restrict__ beta_1,
    const float* __restrict__ alpha_2,
    const float* __restrict__ beta_2,
    f32x4* __restrict__ out,
    long long n4)           // elements per timestep plane, in float4 units
{
    const long long i = (long long)blockIdx.x * blockDim.x + threadIdx.x;
    if (i >= n4) return;

    // scalar gates: broadcast loads (L2-hit), computed once per thread
    const float a1 = 1.0f / (1.0f + expf(-alpha_1[0])) - 0.5f;
    const float b1 = 1.0f / (1.0f + expf(-beta_1[0]))  - 0.5f;
    const float a2 = 1.0f / (1.0f + expf(-alpha_2[0])) + 0.5f;
    const float b2 = 1.0f / (1.0f + expf(-beta_2[0]))  + 0.5f;

    const f32x4* xp = x + i;
    f32x4*       op = out + i;

    f32x4 vd = (f32x4)(0.0f);
    f32x4 vs = (f32x4)(0.5f * V_TH);

    // x and out are pure streams (537 MB >> 32 MB L2): bypass temporal caching.
    #pragma unroll
    for (int t = 0; t < T_STEPS; ++t) {
        f32x4 xv = __builtin_nontemporal_load(xp);
        xp += n4;
        f32x4 o;

        #pragma unroll
        for (int c = 0; c < 4; ++c) {
            vd[c] = a1 * vd[c] + b1 * vs[c] + xv[c];
            vs[c] = a2 * vs[c] + b2 * vd[c];
            float s = (vs[c] - V_TH >= 0.0f) ? V_TH : 0.0f;
            o[c] = s;
            vs[c] -= s;
        }

        __builtin_nontemporal_store(o, op);
        op += n4;
    }
}

// scalar tail kernel (robustness; unused when plane size % 4 == 0)
__global__ __launch_bounds__(64) void OnlineNeuron_tail(
    const float* __restrict__ x,
    const float* __restrict__ alpha_1,
    const float* __restrict__ beta_1,
    const float* __restrict__ alpha_2,
    const float* __restrict__ beta_2,
    float* __restrict__ out,
    long long base, long long n)   // elements [base, base+n) of each plane
{
    const float a1 = 1.0f / (1.0f + expf(-alpha_1[0])) - 0.5f;
    const float b1 = 1.0f / (1.0f + expf(-beta_1[0]))  - 0.5f;
    const float a2 = 1.0f / (1.0f + expf(-alpha_2[0])) + 0.5f;
    const float b2 = 1.0f / (1.0f + expf(-beta_2[0]))  + 0.5f;
    const long long nplane = base + n;

    long long i = (long long)blockIdx.x * blockDim.x + threadIdx.x;
    if (i >= n) return;
    long long idx = base + i;

    float vd = 0.f, vs = 0.5f * V_TH;
    #pragma unroll
    for (int t = 0; t < T_STEPS; ++t) {
        float xv = x[(long long)t * nplane + idx];
        vd = a1 * vd + b1 * vs + xv;
        vs = a2 * vs + b2 * vd;
        float s = (vs - V_TH >= 0.0f) ? V_TH : 0.0f;
        out[(long long)t * nplane + idx] = s;
        vs -= s;
    }
}

extern "C" void kernel_launch(void* const* d_in, const int* in_sizes, int n_in,
                              void* d_out, int out_size, void* d_ws, size_t ws_size,
                              hipStream_t stream) {
    const float* x  = (const float*)d_in[0];
    const float* a1 = (const float*)d_in[1];
    const float* b1 = (const float*)d_in[2];
    const float* a2 = (const float*)d_in[3];
    const float* b2 = (const float*)d_in[4];
    float* out = (float*)d_out;

    const long long total = (long long)in_sizes[0];
    const long long N     = total / T_STEPS;   // elements per timestep plane
    const long long n4    = N / 4;             // float4 units per plane
    const long long tail  = N - n4 * 4;

    const int block = 256;
    long long blocks = (n4 + block - 1) / block;   // exact grid: one tile/thread
    if (blocks < 1) blocks = 1;

    OnlineNeuron_kernel<<<(int)blocks, block, 0, stream>>>(
        (const f32x4*)x, a1, b1, a2, b2, (f32x4*)out, n4);

    if (tail > 0) {
        int tgrid = (int)((tail + 63) / 64);
        OnlineNeuron_tail<<<tgrid, 64, 0, stream>>>(
            x, a1, b1, a2, b2, out, n4 * 4, tail);
    }
}